// Round 1
// 7216.557 us; speedup vs baseline: 1.1146x; 1.1146x over previous
//
#include <hip/hip_runtime.h>
#include <stdint.h>

#define E_DIM 2048
#define H_DIM 2048
#define B_DIM 512
#define T_DIM 256
#define G4H   8192  // 4*H

typedef unsigned short u16;
typedef __attribute__((ext_vector_type(8))) short bf16x8;
typedef __attribute__((ext_vector_type(4))) float f32x4;

__device__ inline u16 f2b(float f) {
  union { float f; uint32_t i; } v; v.f = f;
  uint32_t u = v.i;
  return (u16)((u + 0x7FFFu + ((u >> 16) & 1u)) >> 16);  // RNE
}
__device__ inline float b2f(u16 u) {
  union { uint32_t i; float f; } v; v.i = ((uint32_t)u) << 16; return v.f;
}

__device__ __forceinline__ void stage16(const void* g, void* l) {
  __builtin_amdgcn_global_load_lds(
      (const __attribute__((address_space(1))) uint32_t*)g,
      (__attribute__((address_space(3))) uint32_t*)l, 16, 0, 0);
}

__global__ __launch_bounds__(256) void convert_bf16(const float* __restrict__ s,
                                                    u16* __restrict__ d, int n4) {
  int i = blockIdx.x * 256 + threadIdx.x;
  if (i < n4) {
    float4 f = ((const float4*)s)[i];
    ushort4 o;
    o.x = f2b(f.x); o.y = f2b(f.y); o.z = f2b(f.z); o.w = f2b(f.w);
    ((ushort4*)d)[i] = o;
  }
}

// W_eff = W_hh + W_ih @ W_out (rank-2 fold), MFMA-B-fragment order. [verified r5/r6]
__global__ __launch_bounds__(256) void build_weff(const float* __restrict__ W,
                                                  const float* __restrict__ W_ih,
                                                  const float* __restrict__ W_out,
                                                  u16* __restrict__ Wz) {
  int id = blockIdx.x * 256 + threadIdx.x;     // chunk id, total 2M
  int lane = id & 63;
  int k32  = (id >> 6) & 63;
  int n16  = id >> 12;
  int np = n16 * 16 + (lane & 15);
  int k  = k32 * 32 + (lane >> 4) * 8;
  int g = np & 3, jrow = np >> 2;
  int src = g * H_DIM + jrow;
  float wi0 = W_ih[src * 2 + 0], wi1 = W_ih[src * 2 + 1];
  const float* sw = W + (size_t)src * H_DIM + k;
  u16 out[8];
  for (int j = 0; j < 8; ++j) {
    float v = sw[j] + wi0 * W_out[k + j] + wi1 * W_out[H_DIM + k + j];
    out[j] = f2b(v);
  }
  u16* dst = Wz + (size_t)id * 8;
  *(ushort4*)(dst) = *(ushort4*)&out[0];
  *(ushort4*)(dst + 4) = *(ushort4*)&out[4];
}

// epi[n'] = {b_ih+b_hh+b_out@W_ih^T, W_ih[:,0], W_ih[:,1], 0}   [verified r5/r6]
__global__ __launch_bounds__(256) void build_epi(const float* __restrict__ b_ih,
                                                 const float* __restrict__ b_hh,
                                                 const float* __restrict__ W_ih,
                                                 const float* __restrict__ b_out,
                                                 float* __restrict__ epi) {
  int np = blockIdx.x * 256 + threadIdx.x;
  int src = (np & 3) * H_DIM + (np >> 2);
  float wi0 = W_ih[src * 2 + 0], wi1 = W_ih[src * 2 + 1];
  float4 e;
  e.x = b_ih[src] + b_hh[src] + b_out[0] * wi0 + b_out[1] * wi1;
  e.y = wi0;
  e.z = wi1;
  e.w = 0.f;
  ((float4*)epi)[np] = e;
}

// ---- plain GEMM (h0 path, runs once) ----
#define BM 64
#define BN 128
#define BK 32
__global__ __launch_bounds__(256) void gemm_bt(const u16* __restrict__ A,
                                               const u16* __restrict__ Bm,
                                               float* __restrict__ C,
                                               int M, int N, int K) {
  __shared__ u16 sA[BM * BK];
  __shared__ u16 sB[BN * BK];
  const int t = threadIdx.x;
  const int bm0 = blockIdx.y * BM, bn0 = blockIdx.x * BN;
  const int wave = t >> 6, lane = t & 63;
  const int wm = (wave >> 1) * 32, wn = (wave & 1) * 64;
  const int r16 = lane & 15, quad = lane >> 4;

  f32x4 acc[2][4];
  const f32x4 z = {0.f, 0.f, 0.f, 0.f};
  for (int i = 0; i < 2; ++i)
    for (int j = 0; j < 4; ++j) acc[i][j] = z;

  const int arow = t >> 2, acg = t & 3;

  for (int k0 = 0; k0 < K; k0 += BK) {
    __syncthreads();
    *(uint4*)&sA[arow * BK + acg * 8] =
        *(const uint4*)&A[(size_t)(bm0 + arow) * K + k0 + acg * 8];
    for (int i = 0; i < 2; ++i) {
      int c = t + 256 * i;
      int row = c >> 2, cg = c & 3;
      *(uint4*)&sB[row * BK + cg * 8] =
          *(const uint4*)&Bm[(size_t)(bn0 + row) * K + k0 + cg * 8];
    }
    __syncthreads();
    bf16x8 af[2], bfr[4];
    for (int mt = 0; mt < 2; ++mt)
      af[mt] = *(const bf16x8*)&sA[(wm + mt * 16 + r16) * BK + quad * 8];
    for (int nt = 0; nt < 4; ++nt)
      bfr[nt] = *(const bf16x8*)&sB[(wn + nt * 16 + r16) * BK + quad * 8];
    for (int mt = 0; mt < 2; ++mt)
      for (int nt = 0; nt < 4; ++nt)
        acc[mt][nt] = __builtin_amdgcn_mfma_f32_16x16x32_bf16(af[mt], bfr[nt],
                                                              acc[mt][nt], 0, 0, 0);
  }
  for (int mt = 0; mt < 2; ++mt)
    for (int nt = 0; nt < 4; ++nt) {
      int row = bm0 + wm + mt * 16 + quad * 4;
      int col = bn0 + wn + nt * 16 + r16;
      for (int r = 0; r < 4; ++r)
        C[(size_t)(row + r) * N + col] = acc[mt][nt][r];
    }
}

// h0pre + b_embed -> h fragment layout; c=0; xzero=0.
__global__ __launch_bounds__(256) void init_state(const float* __restrict__ h0pre,
                                                  const float* __restrict__ b_embed,
                                                  u16* __restrict__ h,
                                                  float* __restrict__ c,
                                                  float* __restrict__ xzero) {
  int idx = blockIdx.x * 256 + threadIdx.x;  // B*H
  int bg = idx >> 11, k = idx & (H_DIM - 1);
  float v = h0pre[idx] + b_embed[k];
  size_t chunk = (((size_t)(bg >> 4)) * 64 + (k >> 5)) * 64 + ((k >> 3) & 3) * 16 + (bg & 15);
  size_t pos = chunk * 8 + (k & 7);
  h[pos] = f2b(v);
  c[pos] = 0.f;
  if (idx < B_DIM * 2) xzero[idx] = 0.f;
}

// xcorr[m] = -(h0[m] @ W_out^T + b_out)   [verified r5/r6]
__global__ __launch_bounds__(64) void calc_xcorr(const float* __restrict__ h0pre,
                                                 const float* __restrict__ b_embed,
                                                 const float* __restrict__ W_out,
                                                 const float* __restrict__ b_out,
                                                 float* __restrict__ xc) {
  int m = blockIdx.x, ln = threadIdx.x;
  float s0 = 0.f, s1 = 0.f;
  for (int k = ln; k < H_DIM; k += 64) {
    float hv = h0pre[(size_t)m * H_DIM + k] + b_embed[k];
    s0 += hv * W_out[k];
    s1 += hv * W_out[H_DIM + k];
  }
  for (int off = 32; off > 0; off >>= 1) {
    s0 += __shfl_down(s0, off);
    s1 += __shfl_down(s1, off);
  }
  if (ln == 0) {
    xc[m * 2 + 0] = -(s0 + b_out[0]);
    xc[m * 2 + 1] = -(s1 + b_out[1]);
  }
}

// seed outputs with biases (epilogue atomics add partial dots onto these)
__global__ __launch_bounds__(256) void init_out(const float* __restrict__ b_out,
                                                const float* __restrict__ b_stop,
                                                float* __restrict__ coords,
                                                float* __restrict__ stops) {
  int i = blockIdx.x * 256 + threadIdx.x;      // B*T
  coords[i * 2 + 0] = b_out[0];
  coords[i * 2 + 1] = b_out[1];
  stops[i] = b_stop[0];
}

__global__ __launch_bounds__(256) void finalize_stops(float* __restrict__ stops) {
  int i = blockIdx.x * 256 + threadIdx.x;      // B*T
  stops[i] = 1.f / (1.f + __expf(-stops[i]));
}

// ---- fused step: LDS-staged double-buffered GEMM + LSTM + heads ----
// Block tile 128(m) x 128(n'). 8 waves: kq = wv>>2 (K/2 half), wm=(wv>>1)&1,
// wn=wv&1 -> 64x64 wave tile over K=1024. global_load_lds 16B staging, BK=64,
// one LDS K-combine round, single-pass 8-wave epilogue.
// LDS map (128 KiB): region(kq,buf) at (kq*2+buf)*32KiB; within region:
//   A tiles [mc(0..7)*2+kc2]*1KiB at +0, B tiles at +16KiB. Each 1KiB tile is
//   the fragment-ordered 16x32 chunk (lane ln reads bytes ln*16..ln*16+16).
__global__ __launch_bounds__(512, 2) void gemm_lstm(const u16* __restrict__ hA,
                                                 const u16* __restrict__ Wz,
                                                 const float* __restrict__ epi,
                                                 const float* __restrict__ x,
                                                 float* __restrict__ c,
                                                 u16* __restrict__ h_out,
                                                 const float* __restrict__ W_out,
                                                 const float* __restrict__ W_stop,
                                                 float* __restrict__ coords,
                                                 float* __restrict__ stops,
                                                 int trow) {
  __shared__ __align__(16) char smem[131072];  // 4 x 32 KB stage bufs; cb/gt aliased

  const int bid = blockIdx.x;
  const int nt = (bid & 7) * 8 + ((bid >> 3) & 7);   // XCD-pinned n-tile
  const int mt = bid >> 6;
  const int bm0 = mt * 128;

  const int t = threadIdx.x, wv = t >> 6, ln = t & 63;
  const int kq = wv >> 2, wm = (wv >> 1) & 1, wn = wv & 1;
  const int r16 = ln & 15, quad = ln >> 4;

  // --- staging descriptors: 8 x 1KiB tiles per wave per phase (64 total) ---
  // tile id ti = wv*8+s; group g=ti>>4: 0=A(kq0) 1=B(kq0) 2=A(kq1) 3=B(kq1);
  // w=ti&15: rowi=w>>1 (m- or n-chunk), kc2=w&1.
  const u16* gptr[8];
  uint32_t ldsoff[8];
#pragma unroll
  for (int s = 0; s < 8; ++s) {
    int ti = wv * 8 + s;
    int g = ti >> 4;
    int w = ti & 15;
    int rowi = w >> 1, kc2 = w & 1;
    int kqg = g >> 1, isB = g & 1;
    int kc = kqg * 32 + kc2;                    // phase-0 kc
    if (isB)
      gptr[s] = Wz + ((size_t)(nt * 8 + rowi) * 64 + kc) * 512 + ln * 8;
    else
      gptr[s] = hA + ((size_t)((bm0 >> 4) + rowi) * 64 + kc) * 512 + ln * 8;
    ldsoff[s] = (uint32_t)(kqg * 65536 + isB * 16384 + w * 1024);
  }

  // prologue: stage phase 0 into buf 0
#pragma unroll
  for (int s = 0; s < 8; ++s) stage16(gptr[s], smem + ldsoff[s]);
#pragma unroll
  for (int s = 0; s < 8; ++s) gptr[s] += 1024;   // advance kc by 2 (2 KiB)
  __syncthreads();

  f32x4 acc[4][4];
  const f32x4 z = {0.f, 0.f, 0.f, 0.f};
#pragma unroll
  for (int i = 0; i < 4; ++i)
#pragma unroll
    for (int j = 0; j < 4; ++j) acc[i][j] = z;

  const uint32_t rdbase0 = (uint32_t)(kq * 65536);

  for (int p = 0; p < 16; ++p) {
    if (p < 15) {                                // stage phase p+1
      const uint32_t tog = (uint32_t)(((p + 1) & 1) * 32768);
#pragma unroll
      for (int s = 0; s < 8; ++s) stage16(gptr[s], smem + (ldsoff[s] + tog));
#pragma unroll
      for (int s = 0; s < 8; ++s) gptr[s] += 1024;
    }
    const char* rb = smem + rdbase0 + (uint32_t)((p & 1) * 32768);
#pragma unroll
    for (int kc2 = 0; kc2 < 2; ++kc2) {
      bf16x8 af[4], bf[4];
#pragma unroll
      for (int i = 0; i < 4; ++i)
        af[i] = *(const bf16x8*)(rb + ((wm * 4 + i) * 2 + kc2) * 1024 + ln * 16);
#pragma unroll
      for (int i = 0; i < 4; ++i)
        bf[i] = *(const bf16x8*)(rb + 16384 + ((wn * 4 + i) * 2 + kc2) * 1024 + ln * 16);
#pragma unroll
      for (int mi = 0; mi < 4; ++mi)
#pragma unroll
        for (int ni = 0; ni < 4; ++ni)
          acc[mi][ni] = __builtin_amdgcn_mfma_f32_16x16x32_bf16(af[mi], bf[ni],
                                                                acc[mi][ni], 0, 0, 0);
    }
    __syncthreads();  // drains vmcnt(0): p+1 stages landed; all reads of cur done
  }

  // --- K-combine: kq=1 exports 64 KiB, kq=0 adds -> kq=0 holds full-K acc ---
  float* cb = (float*)smem;
  if (kq == 1) {
    float* dst = cb + (wm * 2 + wn) * 4096;
#pragma unroll
    for (int mi = 0; mi < 4; ++mi)
#pragma unroll
      for (int ni = 0; ni < 4; ++ni)
        *(f32x4*)&dst[((mi * 4 + ni) * 64 + ln) * 4] = acc[mi][ni];
  }
  __syncthreads();
  if (kq == 0) {
    const float* src = cb + (wm * 2 + wn) * 4096;
#pragma unroll
    for (int mi = 0; mi < 4; ++mi)
#pragma unroll
      for (int ni = 0; ni < 4; ++ni)
        acc[mi][ni] += *(const f32x4*)&src[((mi * 4 + ni) * 64 + ln) * 4];
  }
  __syncthreads();

  // --- gate tile to LDS (full 128 x 132 f32), written by the 4 kq=0 waves ---
  float* gt = (float*)smem;
  if (kq == 0) {
#pragma unroll
    for (int mi = 0; mi < 4; ++mi)
#pragma unroll
      for (int ni = 0; ni < 4; ++ni) {
        int row = wm * 64 + mi * 16 + quad * 4;
        int col = wn * 64 + ni * 16 + r16;
        f32x4 v = acc[mi][ni];
#pragma unroll
        for (int r = 0; r < 4; ++r)
          gt[(row + r) * 132 + col] = v[r];
      }
  }
  __syncthreads();

  // --- single-pass epilogue: all 8 waves; wave wv owns rows wv*16 + r16 ---
  {
    const int lrow = wv * 16 + r16;              // 0..127
    const int bg = bm0 + lrow;
    const float x0 = x[bg * 2 + 0], x1 = x[bg * 2 + 1];
    const size_t chunk = (((size_t)(bg >> 4)) * 64 + nt) * 64 + ln;
    const int hc0 = nt * 32 + quad * 8;
    float cv[8]; u16 hv[8];
    float s0 = 0.f, s1 = 0.f, s2 = 0.f;
    const float4* epi4 = (const float4*)epi;
    f32x4 cold0 = *(const f32x4*)&c[chunk * 8 + 0];
    f32x4 cold1 = *(const f32x4*)&c[chunk * 8 + 4];
#pragma unroll
    for (int j = 0; j < 8; ++j) {
      int col = quad * 32 + j * 4;
      float4 g4 = *(const float4*)&gt[lrow * 132 + col];
      float4 e0 = epi4[nt * 128 + col + 0];
      float4 e1 = epi4[nt * 128 + col + 1];
      float4 e2 = epi4[nt * 128 + col + 2];
      float4 e3 = epi4[nt * 128 + col + 3];
      float gi = g4.x + e0.x + x0 * e0.y + x1 * e0.z;
      float gf = g4.y + e1.x + x0 * e1.y + x1 * e1.z;
      float gg = g4.z + e2.x + x0 * e2.y + x1 * e2.z;
      float go = g4.w + e3.x + x0 * e3.y + x1 * e3.z;
      float si = 1.f / (1.f + __expf(-gi));
      float sf = 1.f / (1.f + __expf(-gf));
      float so = 1.f / (1.f + __expf(-go));
      float cold = (j < 4) ? cold0[j & 3] : cold1[j & 3];
      float cn = sf * cold + si * tanhf(gg);
      cv[j] = cn;
      float hf = so * tanhf(cn);
      hv[j] = f2b(hf);
      s0 += hf * W_out[hc0 + j];
      s1 += hf * W_out[H_DIM + hc0 + j];
      s2 += hf * W_stop[hc0 + j];
    }
    *(float4*)&c[chunk * 8 + 0] = *(float4*)&cv[0];
    *(float4*)&c[chunk * 8 + 4] = *(float4*)&cv[4];
    *(ushort4*)&h_out[chunk * 8 + 0] = *(ushort4*)&hv[0];
    *(ushort4*)&h_out[chunk * 8 + 4] = *(ushort4*)&hv[4];
    s0 += __shfl_xor(s0, 16); s1 += __shfl_xor(s1, 16); s2 += __shfl_xor(s2, 16);
    s0 += __shfl_xor(s0, 32); s1 += __shfl_xor(s1, 32); s2 += __shfl_xor(s2, 32);
    if (quad == 0) {
      atomicAdd(&coords[((size_t)bg * T_DIM + trow) * 2 + 0], s0);
      atomicAdd(&coords[((size_t)bg * T_DIM + trow) * 2 + 1], s1);
      atomicAdd(&stops[(size_t)bg * T_DIM + trow], s2);
    }
  }
}

extern "C" void kernel_launch(void* const* d_in, const int* in_sizes, int n_in,
                              void* d_out, int out_size, void* d_ws, size_t ws_size,
                              hipStream_t stream) {
  const float* embedding = (const float*)d_in[0];
  const float* W_embed   = (const float*)d_in[2];
  const float* b_embed   = (const float*)d_in[3];
  const float* W_ih      = (const float*)d_in[4];
  const float* b_ih      = (const float*)d_in[5];
  const float* W_hh      = (const float*)d_in[6];
  const float* b_hh      = (const float*)d_in[7];
  const float* W_out     = (const float*)d_in[8];
  const float* b_out     = (const float*)d_in[9];
  const float* W_stop    = (const float*)d_in[10];
  const float* b_stop    = (const float*)d_in[11];

  float* coords = (float*)d_out;
  float* stops  = (float*)d_out + (size_t)B_DIM * T_DIM * 2;

  char* ws = (char*)d_ws;
  u16* W_z     = (u16*)ws;   ws += (size_t)G4H * H_DIM * 2;    // 32 MB
  u16* W_emb_b = (u16*)ws;   ws += (size_t)H_DIM * E_DIM * 2;  // 8 MB
  u16* emb_b   = (u16*)ws;   ws += (size_t)B_DIM * E_DIM * 2;  // 2 MB
  float* h0pre = (float*)ws; ws += (size_t)B_DIM * H_DIM * 4;  // 4 MB
  float* epi   = (float*)ws; ws += (size_t)G4H * 4 * 4;        // 128 KB
  float* cbuf  = (float*)ws; ws += (size_t)B_DIM * H_DIM * 4;  // 4 MB
  u16* hbuf0   = (u16*)ws;   ws += (size_t)B_DIM * H_DIM * 2;  // 2 MB
  u16* hbuf1   = (u16*)ws;   ws += (size_t)B_DIM * H_DIM * 2;  // 2 MB
  float* xcorr = (float*)ws; ws += (size_t)B_DIM * 2 * 4;
  float* xzero = (float*)ws; ws += (size_t)B_DIM * 2 * 4;

  convert_bf16<<<(B_DIM * E_DIM / 4 + 255) / 256, 256, 0, stream>>>(embedding, emb_b, B_DIM * E_DIM / 4);
  convert_bf16<<<(H_DIM * E_DIM / 4 + 255) / 256, 256, 0, stream>>>(W_embed, W_emb_b, H_DIM * E_DIM / 4);
  build_weff<<<(G4H * H_DIM / 8) / 256, 256, 0, stream>>>(W_hh, W_ih, W_out, W_z);
  build_epi<<<G4H / 256, 256, 0, stream>>>(b_ih, b_hh, W_ih, b_out, epi);
  init_out<<<(B_DIM * T_DIM) / 256, 256, 0, stream>>>(b_out, b_stop, coords, stops);

  gemm_bt<<<dim3(H_DIM / BN, B_DIM / BM), 256, 0, stream>>>(emb_b, W_emb_b, h0pre,
                                                            B_DIM, H_DIM, E_DIM);
  init_state<<<(B_DIM * H_DIM) / 256, 256, 0, stream>>>(h0pre, b_embed, hbuf0, cbuf, xzero);
  calc_xcorr<<<B_DIM, 64, 0, stream>>>(h0pre, b_embed, W_out, b_out, xcorr);

  for (int t = 0; t < T_DIM; ++t) {
    u16* h_in  = (t & 1) ? hbuf1 : hbuf0;
    u16* h_out = (t & 1) ? hbuf0 : hbuf1;
    const float* xv = (t == 0) ? xcorr : xzero;
    gemm_lstm<<<256, 512, 0, stream>>>(h_in, W_z, epi, xv, cbuf, h_out,
                                       W_out, W_stop, coords, stops, t);
  }
  finalize_stops<<<(B_DIM * T_DIM) / 256, 256, 0, stream>>>(stops);
}

// Round 2
// 7013.542 us; speedup vs baseline: 1.1469x; 1.0289x over previous
//
#include <hip/hip_runtime.h>
#include <stdint.h>

#define E_DIM 2048
#define H_DIM 2048
#define B_DIM 512
#define T_DIM 256
#define G4H   8192  // 4*H

typedef unsigned short u16;
typedef __attribute__((ext_vector_type(8))) short bf16x8;
typedef __attribute__((ext_vector_type(4))) float f32x4;

__device__ inline u16 f2b(float f) {
  union { float f; uint32_t i; } v; v.f = f;
  uint32_t u = v.i;
  return (u16)((u + 0x7FFFu + ((u >> 16) & 1u)) >> 16);  // RNE
}
__device__ inline float b2f(u16 u) {
  union { uint32_t i; float f; } v; v.i = ((uint32_t)u) << 16; return v.f;
}

__device__ __forceinline__ void stage16(const void* g, void* l) {
  __builtin_amdgcn_global_load_lds(
      (const __attribute__((address_space(1))) uint32_t*)g,
      (__attribute__((address_space(3))) uint32_t*)l, 16, 0, 0);
}

__global__ __launch_bounds__(256) void convert_bf16(const float* __restrict__ s,
                                                    u16* __restrict__ d, int n4) {
  int i = blockIdx.x * 256 + threadIdx.x;
  if (i < n4) {
    float4 f = ((const float4*)s)[i];
    ushort4 o;
    o.x = f2b(f.x); o.y = f2b(f.y); o.z = f2b(f.z); o.w = f2b(f.w);
    ((ushort4*)d)[i] = o;
  }
}

// W_eff = W_hh + W_ih @ W_out (rank-2 fold), MFMA-B-fragment order. [verified r5/r6]
__global__ __launch_bounds__(256) void build_weff(const float* __restrict__ W,
                                                  const float* __restrict__ W_ih,
                                                  const float* __restrict__ W_out,
                                                  u16* __restrict__ Wz) {
  int id = blockIdx.x * 256 + threadIdx.x;     // chunk id, total 2M
  int lane = id & 63;
  int k32  = (id >> 6) & 63;
  int n16  = id >> 12;
  int np = n16 * 16 + (lane & 15);
  int k  = k32 * 32 + (lane >> 4) * 8;
  int g = np & 3, jrow = np >> 2;
  int src = g * H_DIM + jrow;
  float wi0 = W_ih[src * 2 + 0], wi1 = W_ih[src * 2 + 1];
  const float* sw = W + (size_t)src * H_DIM + k;
  u16 out[8];
  for (int j = 0; j < 8; ++j) {
    float v = sw[j] + wi0 * W_out[k + j] + wi1 * W_out[H_DIM + k + j];
    out[j] = f2b(v);
  }
  u16* dst = Wz + (size_t)id * 8;
  *(ushort4*)(dst) = *(ushort4*)&out[0];
  *(ushort4*)(dst + 4) = *(ushort4*)&out[4];
}

// epi[n'] = {b_ih+b_hh+b_out@W_ih^T, W_ih[:,0], W_ih[:,1], 0}   [verified r5/r6]
__global__ __launch_bounds__(256) void build_epi(const float* __restrict__ b_ih,
                                                 const float* __restrict__ b_hh,
                                                 const float* __restrict__ W_ih,
                                                 const float* __restrict__ b_out,
                                                 float* __restrict__ epi) {
  int np = blockIdx.x * 256 + threadIdx.x;
  int src = (np & 3) * H_DIM + (np >> 2);
  float wi0 = W_ih[src * 2 + 0], wi1 = W_ih[src * 2 + 1];
  float4 e;
  e.x = b_ih[src] + b_hh[src] + b_out[0] * wi0 + b_out[1] * wi1;
  e.y = wi0;
  e.z = wi1;
  e.w = 0.f;
  ((float4*)epi)[np] = e;
}

// ---- plain GEMM (h0 path, runs once) ----
#define BM 64
#define BN 128
#define BK 32
__global__ __launch_bounds__(256) void gemm_bt(const u16* __restrict__ A,
                                               const u16* __restrict__ Bm,
                                               float* __restrict__ C,
                                               int M, int N, int K) {
  __shared__ u16 sA[BM * BK];
  __shared__ u16 sB[BN * BK];
  const int t = threadIdx.x;
  const int bm0 = blockIdx.y * BM, bn0 = blockIdx.x * BN;
  const int wave = t >> 6, lane = t & 63;
  const int wm = (wave >> 1) * 32, wn = (wave & 1) * 64;
  const int r16 = lane & 15, quad = lane >> 4;

  f32x4 acc[2][4];
  const f32x4 z = {0.f, 0.f, 0.f, 0.f};
  for (int i = 0; i < 2; ++i)
    for (int j = 0; j < 4; ++j) acc[i][j] = z;

  const int arow = t >> 2, acg = t & 3;

  for (int k0 = 0; k0 < K; k0 += BK) {
    __syncthreads();
    *(uint4*)&sA[arow * BK + acg * 8] =
        *(const uint4*)&A[(size_t)(bm0 + arow) * K + k0 + acg * 8];
    for (int i = 0; i < 2; ++i) {
      int c = t + 256 * i;
      int row = c >> 2, cg = c & 3;
      *(uint4*)&sB[row * BK + cg * 8] =
          *(const uint4*)&Bm[(size_t)(bn0 + row) * K + k0 + cg * 8];
    }
    __syncthreads();
    bf16x8 af[2], bfr[4];
    for (int mt = 0; mt < 2; ++mt)
      af[mt] = *(const bf16x8*)&sA[(wm + mt * 16 + r16) * BK + quad * 8];
    for (int nt = 0; nt < 4; ++nt)
      bfr[nt] = *(const bf16x8*)&sB[(wn + nt * 16 + r16) * BK + quad * 8];
    for (int mt = 0; mt < 2; ++mt)
      for (int nt = 0; nt < 4; ++nt)
        acc[mt][nt] = __builtin_amdgcn_mfma_f32_16x16x32_bf16(af[mt], bfr[nt],
                                                              acc[mt][nt], 0, 0, 0);
  }
  for (int mt = 0; mt < 2; ++mt)
    for (int nt = 0; nt < 4; ++nt) {
      int row = bm0 + wm + mt * 16 + quad * 4;
      int col = bn0 + wn + nt * 16 + r16;
      for (int r = 0; r < 4; ++r)
        C[(size_t)(row + r) * N + col] = acc[mt][nt][r];
    }
}

// h0pre + b_embed -> h fragment layout; c=0; xzero=0.
__global__ __launch_bounds__(256) void init_state(const float* __restrict__ h0pre,
                                                  const float* __restrict__ b_embed,
                                                  u16* __restrict__ h,
                                                  float* __restrict__ c,
                                                  float* __restrict__ xzero) {
  int idx = blockIdx.x * 256 + threadIdx.x;  // B*H
  int bg = idx >> 11, k = idx & (H_DIM - 1);
  float v = h0pre[idx] + b_embed[k];
  size_t chunk = (((size_t)(bg >> 4)) * 64 + (k >> 5)) * 64 + ((k >> 3) & 3) * 16 + (bg & 15);
  size_t pos = chunk * 8 + (k & 7);
  h[pos] = f2b(v);
  c[pos] = 0.f;
  if (idx < B_DIM * 2) xzero[idx] = 0.f;
}

// xcorr[m] = -(h0[m] @ W_out^T + b_out)   [verified r5/r6]
__global__ __launch_bounds__(64) void calc_xcorr(const float* __restrict__ h0pre,
                                                 const float* __restrict__ b_embed,
                                                 const float* __restrict__ W_out,
                                                 const float* __restrict__ b_out,
                                                 float* __restrict__ xc) {
  int m = blockIdx.x, ln = threadIdx.x;
  float s0 = 0.f, s1 = 0.f;
  for (int k = ln; k < H_DIM; k += 64) {
    float hv = h0pre[(size_t)m * H_DIM + k] + b_embed[k];
    s0 += hv * W_out[k];
    s1 += hv * W_out[H_DIM + k];
  }
  for (int off = 32; off > 0; off >>= 1) {
    s0 += __shfl_down(s0, off);
    s1 += __shfl_down(s1, off);
  }
  if (ln == 0) {
    xc[m * 2 + 0] = -(s0 + b_out[0]);
    xc[m * 2 + 1] = -(s1 + b_out[1]);
  }
}

// seed outputs with biases (epilogue atomics add partial dots onto these)
__global__ __launch_bounds__(256) void init_out(const float* __restrict__ b_out,
                                                const float* __restrict__ b_stop,
                                                float* __restrict__ coords,
                                                float* __restrict__ stops) {
  int i = blockIdx.x * 256 + threadIdx.x;      // B*T
  coords[i * 2 + 0] = b_out[0];
  coords[i * 2 + 1] = b_out[1];
  stops[i] = b_stop[0];
}

__global__ __launch_bounds__(256) void finalize_stops(float* __restrict__ stops) {
  int i = blockIdx.x * 256 + threadIdx.x;      // B*T
  stops[i] = 1.f / (1.f + __expf(-stops[i]));
}

// ---- fused step: deep-pipelined LDS GEMM (T3+T4: counted vmcnt, raw barrier) ----
// Block tile 128(m) x 128(n'). 8 waves: kq = wv>>2 (K/2 half), wm=(wv>>1)&1,
// wn=wv&1 -> 64x64 wave tile over K=1024. 32 phases x 32 KiB, 4 LDS buffers,
// depth-3 prefetch. Per phase: vmcnt(8) [own phase-p loads landed, p+1/p+2 in
// flight] -> raw s_barrier (no auto-drain) -> issue stage(p+3) -> ds_read+MFMA.
// Buffer b = p&3 (32 KiB): kq0A @0, kq0B @8K, kq1A @16K, kq1B @24K; each region
// 8 x 1KiB tiles (16 rows x 32 k, fragment order, lane ln owns bytes ln*16..+16).
__global__ __launch_bounds__(512, 2) void gemm_lstm(const u16* __restrict__ hA,
                                                 const u16* __restrict__ Wz,
                                                 const float* __restrict__ epi,
                                                 const float* __restrict__ x,
                                                 float* __restrict__ c,
                                                 u16* __restrict__ h_out,
                                                 const float* __restrict__ W_out,
                                                 const float* __restrict__ W_stop,
                                                 float* __restrict__ coords,
                                                 float* __restrict__ stops,
                                                 int trow) {
  __shared__ __align__(16) char smem[131072];  // 4 x 32 KB stage bufs; cb/gt aliased

  const int bid = blockIdx.x;
  const int nt = (bid & 7) * 8 + ((bid >> 3) & 7);   // XCD-pinned n-tile
  const int mt = bid >> 6;
  const int bm0 = mt * 128;

  const int t = threadIdx.x, wv = t >> 6, ln = t & 63;
  const int kq = wv >> 2, wm = (wv >> 1) & 1, wn = wv & 1;
  const int r16 = ln & 15, quad = ln >> 4;

  // --- staging descriptors: 4 x 1KiB tiles per wave per phase (32 total) ---
  // ti = wv*4+s; kqg=(ti>>4)&1, isB=(ti>>3)&1, rowi=ti&7.
  const u16* gptr[4];
  uint32_t ldsoff[4];
#pragma unroll
  for (int s = 0; s < 4; ++s) {
    int ti = wv * 4 + s;
    int kqg = (ti >> 4) & 1, isB = (ti >> 3) & 1, rowi = ti & 7;
    int kc0 = kqg * 32;                          // phase-0 k-chunk
    if (isB)
      gptr[s] = Wz + ((size_t)(nt * 8 + rowi) * 64 + kc0) * 512 + ln * 8;
    else
      gptr[s] = hA + ((size_t)((bm0 >> 4) + rowi) * 64 + kc0) * 512 + ln * 8;
    ldsoff[s] = (uint32_t)(kqg * 16384 + isB * 8192 + rowi * 1024);
  }

  f32x4 acc[4][4];
  const f32x4 z = {0.f, 0.f, 0.f, 0.f};
#pragma unroll
  for (int i = 0; i < 4; ++i)
#pragma unroll
    for (int j = 0; j < 4; ++j) acc[i][j] = z;

  const uint32_t rdbase = (uint32_t)(kq * 16384);

#define STAGE_PH(pp)                                                          \
  do {                                                                        \
    const uint32_t _bb = ((uint32_t)(pp) & 3u) * 32768u;                      \
    const size_t _go = (size_t)(pp) * 512;                                    \
    _Pragma("unroll")                                                         \
    for (int s = 0; s < 4; ++s)                                               \
      stage16(gptr[s] + _go, smem + (_bb + ldsoff[s]));                       \
  } while (0)

#define COMPUTE_PH(pp)                                                        \
  do {                                                                        \
    const char* _rb = smem + ((uint32_t)(pp) & 3u) * 32768u + rdbase;         \
    bf16x8 _af[4], _bf[4];                                                    \
    _Pragma("unroll")                                                         \
    for (int i = 0; i < 4; ++i)                                               \
      _af[i] = *(const bf16x8*)(_rb + (wm * 4 + i) * 1024 + ln * 16);         \
    _Pragma("unroll")                                                         \
    for (int i = 0; i < 4; ++i)                                               \
      _bf[i] = *(const bf16x8*)(_rb + 8192 + (wn * 4 + i) * 1024 + ln * 16);  \
    _Pragma("unroll")                                                         \
    for (int mi = 0; mi < 4; ++mi)                                            \
      _Pragma("unroll")                                                       \
      for (int ni = 0; ni < 4; ++ni)                                          \
        acc[mi][ni] = __builtin_amdgcn_mfma_f32_16x16x32_bf16(                \
            _af[mi], _bf[ni], acc[mi][ni], 0, 0, 0);                          \
  } while (0)

  // prologue: stage phases 0..2 (12 loads/wave in flight)
  STAGE_PH(0);
  STAGE_PH(1);
  STAGE_PH(2);

#pragma unroll 4
  for (int p = 0; p < 29; ++p) {
    asm volatile("s_waitcnt vmcnt(8)" ::: "memory");  // own phase-p loads landed
    __builtin_amdgcn_s_barrier();                     // no auto-drain
    STAGE_PH(p + 3);
    COMPUTE_PH(p);
  }
  asm volatile("s_waitcnt vmcnt(8)" ::: "memory");
  __builtin_amdgcn_s_barrier();
  COMPUTE_PH(29);
  asm volatile("s_waitcnt vmcnt(4)" ::: "memory");
  __builtin_amdgcn_s_barrier();
  COMPUTE_PH(30);
  asm volatile("s_waitcnt vmcnt(0)" ::: "memory");
  __builtin_amdgcn_s_barrier();
  COMPUTE_PH(31);
  __syncthreads();

#undef STAGE_PH
#undef COMPUTE_PH

  // --- K-combine: kq=1 exports 64 KiB, kq=0 adds -> kq=0 holds full-K acc ---
  float* cb = (float*)smem;
  if (kq == 1) {
    float* dst = cb + (wm * 2 + wn) * 4096;
#pragma unroll
    for (int mi = 0; mi < 4; ++mi)
#pragma unroll
      for (int ni = 0; ni < 4; ++ni)
        *(f32x4*)&dst[((mi * 4 + ni) * 64 + ln) * 4] = acc[mi][ni];
  }
  __syncthreads();
  if (kq == 0) {
    const float* src = cb + (wm * 2 + wn) * 4096;
#pragma unroll
    for (int mi = 0; mi < 4; ++mi)
#pragma unroll
      for (int ni = 0; ni < 4; ++ni)
        acc[mi][ni] += *(const f32x4*)&src[((mi * 4 + ni) * 64 + ln) * 4];
  }
  __syncthreads();

  // --- gate tile to LDS (full 128 x 132 f32), written by the 4 kq=0 waves ---
  float* gt = (float*)smem;
  if (kq == 0) {
#pragma unroll
    for (int mi = 0; mi < 4; ++mi)
#pragma unroll
      for (int ni = 0; ni < 4; ++ni) {
        int row = wm * 64 + mi * 16 + quad * 4;
        int col = wn * 64 + ni * 16 + r16;
        f32x4 v = acc[mi][ni];
#pragma unroll
        for (int r = 0; r < 4; ++r)
          gt[(row + r) * 132 + col] = v[r];
      }
  }
  __syncthreads();

  // --- single-pass epilogue: all 8 waves; wave wv owns rows wv*16 + r16 ---
  {
    const int lrow = wv * 16 + r16;              // 0..127
    const int bg = bm0 + lrow;
    const float x0 = x[bg * 2 + 0], x1 = x[bg * 2 + 1];
    const size_t chunk = (((size_t)(bg >> 4)) * 64 + nt) * 64 + ln;
    const int hc0 = nt * 32 + quad * 8;
    float cv[8]; u16 hv[8];
    float s0 = 0.f, s1 = 0.f, s2 = 0.f;
    const float4* epi4 = (const float4*)epi;
    f32x4 cold0 = *(const f32x4*)&c[chunk * 8 + 0];
    f32x4 cold1 = *(const f32x4*)&c[chunk * 8 + 4];
#pragma unroll
    for (int j = 0; j < 8; ++j) {
      int col = quad * 32 + j * 4;
      float4 g4 = *(const float4*)&gt[lrow * 132 + col];
      float4 e0 = epi4[nt * 128 + col + 0];
      float4 e1 = epi4[nt * 128 + col + 1];
      float4 e2 = epi4[nt * 128 + col + 2];
      float4 e3 = epi4[nt * 128 + col + 3];
      float gi = g4.x + e0.x + x0 * e0.y + x1 * e0.z;
      float gf = g4.y + e1.x + x0 * e1.y + x1 * e1.z;
      float gg = g4.z + e2.x + x0 * e2.y + x1 * e2.z;
      float go = g4.w + e3.x + x0 * e3.y + x1 * e3.z;
      float si = 1.f / (1.f + __expf(-gi));
      float sf = 1.f / (1.f + __expf(-gf));
      float so = 1.f / (1.f + __expf(-go));
      float cold = (j < 4) ? cold0[j & 3] : cold1[j & 3];
      float cn = sf * cold + si * tanhf(gg);
      cv[j] = cn;
      float hf = so * tanhf(cn);
      hv[j] = f2b(hf);
      s0 += hf * W_out[hc0 + j];
      s1 += hf * W_out[H_DIM + hc0 + j];
      s2 += hf * W_stop[hc0 + j];
    }
    *(float4*)&c[chunk * 8 + 0] = *(float4*)&cv[0];
    *(float4*)&c[chunk * 8 + 4] = *(float4*)&cv[4];
    *(ushort4*)&h_out[chunk * 8 + 0] = *(ushort4*)&hv[0];
    *(ushort4*)&h_out[chunk * 8 + 4] = *(ushort4*)&hv[4];
    s0 += __shfl_xor(s0, 16); s1 += __shfl_xor(s1, 16); s2 += __shfl_xor(s2, 16);
    s0 += __shfl_xor(s0, 32); s1 += __shfl_xor(s1, 32); s2 += __shfl_xor(s2, 32);
    if (quad == 0) {
      atomicAdd(&coords[((size_t)bg * T_DIM + trow) * 2 + 0], s0);
      atomicAdd(&coords[((size_t)bg * T_DIM + trow) * 2 + 1], s1);
      atomicAdd(&stops[(size_t)bg * T_DIM + trow], s2);
    }
  }
}

extern "C" void kernel_launch(void* const* d_in, const int* in_sizes, int n_in,
                              void* d_out, int out_size, void* d_ws, size_t ws_size,
                              hipStream_t stream) {
  const float* embedding = (const float*)d_in[0];
  const float* W_embed   = (const float*)d_in[2];
  const float* b_embed   = (const float*)d_in[3];
  const float* W_ih      = (const float*)d_in[4];
  const float* b_ih      = (const float*)d_in[5];
  const float* W_hh      = (const float*)d_in[6];
  const float* b_hh      = (const float*)d_in[7];
  const float* W_out     = (const float*)d_in[8];
  const float* b_out     = (const float*)d_in[9];
  const float* W_stop    = (const float*)d_in[10];
  const float* b_stop    = (const float*)d_in[11];

  float* coords = (float*)d_out;
  float* stops  = (float*)d_out + (size_t)B_DIM * T_DIM * 2;

  char* ws = (char*)d_ws;
  u16* W_z     = (u16*)ws;   ws += (size_t)G4H * H_DIM * 2;    // 32 MB
  u16* W_emb_b = (u16*)ws;   ws += (size_t)H_DIM * E_DIM * 2;  // 8 MB
  u16* emb_b   = (u16*)ws;   ws += (size_t)B_DIM * E_DIM * 2;  // 2 MB
  float* h0pre = (float*)ws; ws += (size_t)B_DIM * H_DIM * 4;  // 4 MB
  float* epi   = (float*)ws; ws += (size_t)G4H * 4 * 4;        // 128 KB
  float* cbuf  = (float*)ws; ws += (size_t)B_DIM * H_DIM * 4;  // 4 MB
  u16* hbuf0   = (u16*)ws;   ws += (size_t)B_DIM * H_DIM * 2;  // 2 MB
  u16* hbuf1   = (u16*)ws;   ws += (size_t)B_DIM * H_DIM * 2;  // 2 MB
  float* xcorr = (float*)ws; ws += (size_t)B_DIM * 2 * 4;
  float* xzero = (float*)ws; ws += (size_t)B_DIM * 2 * 4;

  convert_bf16<<<(B_DIM * E_DIM / 4 + 255) / 256, 256, 0, stream>>>(embedding, emb_b, B_DIM * E_DIM / 4);
  convert_bf16<<<(H_DIM * E_DIM / 4 + 255) / 256, 256, 0, stream>>>(W_embed, W_emb_b, H_DIM * E_DIM / 4);
  build_weff<<<(G4H * H_DIM / 8) / 256, 256, 0, stream>>>(W_hh, W_ih, W_out, W_z);
  build_epi<<<G4H / 256, 256, 0, stream>>>(b_ih, b_hh, W_ih, b_out, epi);
  init_out<<<(B_DIM * T_DIM) / 256, 256, 0, stream>>>(b_out, b_stop, coords, stops);

  gemm_bt<<<dim3(H_DIM / BN, B_DIM / BM), 256, 0, stream>>>(emb_b, W_emb_b, h0pre,
                                                            B_DIM, H_DIM, E_DIM);
  init_state<<<(B_DIM * H_DIM) / 256, 256, 0, stream>>>(h0pre, b_embed, hbuf0, cbuf, xzero);
  calc_xcorr<<<B_DIM, 64, 0, stream>>>(h0pre, b_embed, W_out, b_out, xcorr);

  for (int t = 0; t < T_DIM; ++t) {
    u16* h_in  = (t & 1) ? hbuf1 : hbuf0;
    u16* h_out = (t & 1) ? hbuf0 : hbuf1;
    const float* xv = (t == 0) ? xcorr : xzero;
    gemm_lstm<<<256, 512, 0, stream>>>(h_in, W_z, epi, xv, cbuf, h_out,
                                       W_out, W_stop, coords, stops, t);
  }
  finalize_stops<<<(B_DIM * T_DIM) / 256, 256, 0, stream>>>(stops);
}